// Round 1
// baseline (527.063 us; speedup 1.0000x reference)
//
#include <hip/hip_runtime.h>
#include <hip/hip_bf16.h>

#define B_  2048
#define T_  200
#define U_  128
#define NB  8      // batch rows per block
#define PITCH 136  // LDS pitch (bf16 elems): 128 + 8 pad to break bank conflicts

typedef __attribute__((ext_vector_type(8))) short short8;
typedef __attribute__((ext_vector_type(4))) short short4_t;
typedef __attribute__((ext_vector_type(4))) float f32x4;

static __device__ inline short f2bf(float f) {
  union { float f; unsigned u; } v; v.f = f;
  unsigned r = v.u + 0x7FFFu + ((v.u >> 16) & 1u);  // RNE
  return (short)(r >> 16);
}
static __device__ inline float sigm(float x) {
  return __builtin_amdgcn_rcpf(1.0f + __builtin_amdgcn_exp2f(x * -1.44269504088896340736f));
}
static __device__ inline float tanh_fast(float x) {
  // tanh(x) = 1 - 2/(exp2(x*2*log2e)+1); saturates correctly at +-inf
  return 1.0f - 2.0f * __builtin_amdgcn_rcpf(1.0f + __builtin_amdgcn_exp2f(x * 2.88539008177792681472f));
}

// out[m][n][k] = bf16(W_m[k][n])  (transposed so B-fragments are contiguous)
// m: 0=W_xu 1=W_xr 2=W_xc 3=W_hu 4=W_hr 5=W_hc
__global__ void prep_weights(const float* __restrict__ Wxu, const float* __restrict__ Wxr,
                             const float* __restrict__ Wxc, const float* __restrict__ Whu,
                             const float* __restrict__ Whr, const float* __restrict__ Whc,
                             short* __restrict__ out) {
  const int m = blockIdx.x >> 7;
  const int n = blockIdx.x & 127;
  const int k = threadIdx.x;
  const float* Wp;
  switch (m) {
    case 0: Wp = Wxu; break; case 1: Wp = Wxr; break; case 2: Wp = Wxc; break;
    case 3: Wp = Whu; break; case 4: Wp = Whr; break; default: Wp = Whc; break;
  }
  out[(m * 128 + n) * 128 + k] = f2bf(Wp[k * 128 + n]);
}

// One block = NB=8 batch rows for all T steps. 4 waves; wave w owns output cols [32w,32w+32).
// All 6 weight matrices register-resident as MFMA B-fragments.
// MFMA 16x16x32 bf16 layouts:
//   A: lane l holds A[l&15][ (l>>4)*8 + j ], j=0..7 (contiguous k)
//   B: lane l holds B[ (l>>4)*8 + j ][ l&15 ]
//   D: lane l reg r holds D[ 4*(l>>4)+r ][ l&15 ]
__global__ __launch_bounds__(256, 1) void augru_scan(
    const float* __restrict__ IS, const float* __restrict__ ATT,
    const float* __restrict__ bxu, const float* __restrict__ bhu,
    const float* __restrict__ bxr, const float* __restrict__ bhr,
    const float* __restrict__ bxc, const float* __restrict__ bhc,
    const short* __restrict__ WT, float* __restrict__ out) {
  __shared__ short h_bf[16][PITCH];
  __shared__ short x_bf[16][PITCH];
  __shared__ short rh_bf[16][PITCH];
  __shared__ float att_s[T_][NB];

  const int tid  = threadIdx.x;
  const int w    = tid >> 6;
  const int l    = tid & 63;
  const int l15  = l & 15;
  const int lg   = l >> 4;
  const int b0   = blockIdx.x * NB;
  const int colb = w * 32;

  // zero LDS staging (rows 8..15 stay zero forever -> garbage M-rows are benign)
  for (int i = tid; i < 16 * PITCH / 2; i += 256) {
    ((int*)h_bf)[i] = 0; ((int*)x_bf)[i] = 0; ((int*)rh_bf)[i] = 0;
  }
  // attention table for this block's rows: att_s[t][r]
  for (int i = tid; i < T_ * NB; i += 256) {
    int r = i / T_, t = i % T_;
    att_s[t][r] = ATT[(size_t)(b0 + r) * T_ + t];
  }
  // stage x_0
  const int prow = tid >> 5;        // 0..7
  const int pc4  = (tid & 31) * 4;  // 0..124
  {
    f32x4 xv = *(const f32x4*)(IS + ((size_t)(b0 + prow) * T_ + 0) * U_ + pc4);
    short4_t xb;
    xb[0] = f2bf(xv[0]); xb[1] = f2bf(xv[1]); xb[2] = f2bf(xv[2]); xb[3] = f2bf(xv[3]);
    *(short4_t*)&x_bf[prow][pc4] = xb;
  }
  // register-resident weight B-fragments: Wf[m][nf][kf]
  short8 Wf[6][2][4];
#pragma unroll
  for (int m = 0; m < 6; ++m)
#pragma unroll
    for (int nf = 0; nf < 2; ++nf)
#pragma unroll
      for (int kf = 0; kf < 4; ++kf) {
        const int col = colb + nf * 16 + l15;
        Wf[m][nf][kf] = *(const short8*)(WT + ((m * 128 + col) * 128 + kf * 32 + lg * 8));
      }
  // fused biases per output col
  float bu[2], br[2], bc[2];
#pragma unroll
  for (int nf = 0; nf < 2; ++nf) {
    const int col = colb + nf * 16 + l15;
    bu[nf] = bxu[col] + bhu[col];
    br[nf] = bxr[col] + bhr[col];
    bc[nf] = bxc[col] + bhc[col];
  }

  const f32x4 fz = {0.0f, 0.0f, 0.0f, 0.0f};
  f32x4 hreg[2]; hreg[0] = fz; hreg[1] = fz;
  float ureg[2][4];

  for (int t = 0; t < T_; ++t) {
    __syncthreads();  // h_bf, x_bf, rh(WAR) ready
    // ---- phase 1: A-fragments + projections + u,r gates ----
    short8 xa[4], ha[4];
#pragma unroll
    for (int kf = 0; kf < 4; ++kf) {
      xa[kf] = *(const short8*)&x_bf[l15][kf * 32 + lg * 8];
      ha[kf] = *(const short8*)&h_bf[l15][kf * 32 + lg * 8];
    }
    // prefetch next step's x (no h dependence)
    const int tn = (t < T_ - 1) ? t + 1 : t;
    f32x4 xnext = *(const f32x4*)(IS + ((size_t)(b0 + prow) * T_ + tn) * U_ + pc4);

    f32x4 axu[2], axr[2], axc[2], ahu[2], ahr[2];
#pragma unroll
    for (int nf = 0; nf < 2; ++nf) { axu[nf] = fz; axr[nf] = fz; axc[nf] = fz; ahu[nf] = fz; ahr[nf] = fz; }
#pragma unroll
    for (int nf = 0; nf < 2; ++nf)
#pragma unroll
      for (int kf = 0; kf < 4; ++kf) {
        axu[nf] = __builtin_amdgcn_mfma_f32_16x16x32_bf16(xa[kf], Wf[0][nf][kf], axu[nf], 0, 0, 0);
        axr[nf] = __builtin_amdgcn_mfma_f32_16x16x32_bf16(xa[kf], Wf[1][nf][kf], axr[nf], 0, 0, 0);
        axc[nf] = __builtin_amdgcn_mfma_f32_16x16x32_bf16(xa[kf], Wf[2][nf][kf], axc[nf], 0, 0, 0);
        ahu[nf] = __builtin_amdgcn_mfma_f32_16x16x32_bf16(ha[kf], Wf[3][nf][kf], ahu[nf], 0, 0, 0);
        ahr[nf] = __builtin_amdgcn_mfma_f32_16x16x32_bf16(ha[kf], Wf[4][nf][kf], ahr[nf], 0, 0, 0);
      }
#pragma unroll
    for (int nf = 0; nf < 2; ++nf)
#pragma unroll
      for (int rg = 0; rg < 4; ++rg) {
        float ug = sigm(axu[nf][rg] + ahu[nf][rg] + bu[nf]);
        float rr = sigm(axr[nf][rg] + ahr[nf][rg] + br[nf]);
        ureg[nf][rg] = ug;
        rh_bf[lg * 4 + rg][colb + nf * 16 + l15] = f2bf(rr * hreg[nf][rg]);
      }
    __syncthreads();  // rh_bf ready; h_bf/x_bf reads done (WAR safe)
    // ---- phase 2: candidate + state update ----
    short8 ra[4];
#pragma unroll
    for (int kf = 0; kf < 4; ++kf) ra[kf] = *(const short8*)&rh_bf[l15][kf * 32 + lg * 8];
    f32x4 ahc[2]; ahc[0] = fz; ahc[1] = fz;
#pragma unroll
    for (int nf = 0; nf < 2; ++nf)
#pragma unroll
      for (int kf = 0; kf < 4; ++kf)
        ahc[nf] = __builtin_amdgcn_mfma_f32_16x16x32_bf16(ra[kf], Wf[5][nf][kf], ahc[nf], 0, 0, 0);
    // attention for this lane's 4 rows: rows (4*lg+rg)&7 == 4*(lg&1)+rg
    f32x4 a4 = *(const f32x4*)&att_s[t][(lg & 1) * 4];
#pragma unroll
    for (int nf = 0; nf < 2; ++nf)
#pragma unroll
      for (int rg = 0; rg < 4; ++rg) {
        float cc = tanh_fast(axc[nf][rg] + ahc[nf][rg] + bc[nf]);
        float au = a4[rg] * ureg[nf][rg];
        float hv = (1.0f - au) * hreg[nf][rg] + au * cc;
        hreg[nf][rg] = hv;
        h_bf[lg * 4 + rg][colb + nf * 16 + l15] = f2bf(hv);
      }
    // stage x_{t+1}
    {
      short4_t xb;
      xb[0] = f2bf(xnext[0]); xb[1] = f2bf(xnext[1]); xb[2] = f2bf(xnext[2]); xb[3] = f2bf(xnext[3]);
      *(short4_t*)&x_bf[prow][pc4] = xb;
    }
  }
  // write h_final (fp32, rows 0..7 real)
#pragma unroll
  for (int nf = 0; nf < 2; ++nf)
#pragma unroll
    for (int rg = 0; rg < 4; ++rg) {
      const int row = lg * 4 + rg;
      if (row < NB) out[(size_t)(b0 + row) * U_ + colb + nf * 16 + l15] = hreg[nf][rg];
    }
}

extern "C" void kernel_launch(void* const* d_in, const int* in_sizes, int n_in,
                              void* d_out, int out_size, void* d_ws, size_t ws_size,
                              hipStream_t stream) {
  const float* IS  = (const float*)d_in[0];
  const float* ATT = (const float*)d_in[1];
  const float* Wxu = (const float*)d_in[2];  const float* bxu = (const float*)d_in[3];
  const float* Whu = (const float*)d_in[4];  const float* bhu = (const float*)d_in[5];
  const float* Wxr = (const float*)d_in[6];  const float* bxr = (const float*)d_in[7];
  const float* Whr = (const float*)d_in[8];  const float* bhr = (const float*)d_in[9];
  const float* Wxc = (const float*)d_in[10]; const float* bxc = (const float*)d_in[11];
  const float* Whc = (const float*)d_in[12]; const float* bhc = (const float*)d_in[13];
  short* WT  = (short*)d_ws;
  float* OUT = (float*)d_out;

  prep_weights<<<dim3(6 * 128), dim3(128), 0, stream>>>(Wxu, Wxr, Wxc, Whu, Whr, Whc, WT);
  augru_scan<<<dim3(B_ / NB), dim3(256), 0, stream>>>(IS, ATT, bxu, bhu, bxr, bhr, bxc, bhc, WT, OUT);
}

// Round 2
// 450.853 us; speedup vs baseline: 1.1690x; 1.1690x over previous
//
#include <hip/hip_runtime.h>
#include <hip/hip_bf16.h>

#define B_  2048
#define T_  200
#define U_  128
#define NB  8      // batch rows per block
#define PITCH 136  // LDS pitch (bf16 elems): 128 + 8 pad

typedef __attribute__((ext_vector_type(8))) short short8;
typedef __attribute__((ext_vector_type(2))) short short2_t;
typedef __attribute__((ext_vector_type(4))) float f32x4;
typedef __attribute__((ext_vector_type(2))) float f32x2;

static __device__ inline short f2bf(float f) {
  union { float f; unsigned u; } v; v.f = f;
  unsigned r = v.u + 0x7FFFu + ((v.u >> 16) & 1u);  // RNE
  return (short)(r >> 16);
}
static __device__ inline float sigm(float x) {
  return __builtin_amdgcn_rcpf(1.0f + __builtin_amdgcn_exp2f(x * -1.44269504088896340736f));
}
static __device__ inline float tanh_fast(float x) {
  return 1.0f - 2.0f * __builtin_amdgcn_rcpf(1.0f + __builtin_amdgcn_exp2f(x * 2.88539008177792681472f));
}

// out[m][n][k] = bf16(W_m[k][n]); coalesced READS (row k contiguous), strided writes.
__global__ void prep_weights(const float* __restrict__ Wxu, const float* __restrict__ Wxr,
                             const float* __restrict__ Wxc, const float* __restrict__ Whu,
                             const float* __restrict__ Whr, const float* __restrict__ Whc,
                             short* __restrict__ out) {
  const int m = blockIdx.x >> 7;   // matrix id
  const int k = blockIdx.x & 127;  // row of W
  const int n = threadIdx.x;       // col of W
  const float* Wp;
  switch (m) {
    case 0: Wp = Wxu; break; case 1: Wp = Wxr; break; case 2: Wp = Wxc; break;
    case 3: Wp = Whu; break; case 4: Wp = Whr; break; default: Wp = Whc; break;
  }
  out[(m * 128 + n) * 128 + k] = f2bf(Wp[k * 128 + n]);
}

// One block = NB=8 batch rows for all T steps. 8 waves x 16 cols (512 thr) ->
// 2 waves/SIMD for latency hiding; total MFMA/VALU work per CU unchanged vs
// 4-wave version. All 6 weight matrices register-resident as B-fragments.
// MFMA 16x16x32 bf16: A: lane l = A[l&15][(l>>4)*8+j]; B: lane l = B[(l>>4)*8+j][l&15];
// D: lane l reg r = D[4*(l>>4)+r][l&15]. Rows 8..15 of the M-tile carry benign garbage
// (row m of D depends only on row m of A; output writes rows<8 only).
__global__ __launch_bounds__(512, 2) void augru_scan(
    const float* __restrict__ IS, const float* __restrict__ ATT,
    const float* __restrict__ bxu, const float* __restrict__ bhu,
    const float* __restrict__ bxr, const float* __restrict__ bhr,
    const float* __restrict__ bxc, const float* __restrict__ bhc,
    const short* __restrict__ WT, float* __restrict__ out) {
  __shared__ short h_bf[16][PITCH];
  __shared__ short x_bf[16][PITCH];
  __shared__ short rh_bf[16][PITCH];
  __shared__ float att_s[T_][NB];

  const int tid  = threadIdx.x;
  const int w    = tid >> 6;        // wave 0..7
  const int l    = tid & 63;
  const int l15  = l & 15;
  const int lg   = l >> 4;
  const int b0   = blockIdx.x * NB;
  const int colb = w * 16;          // 16 output cols per wave
  const int col  = colb + l15;

  // zero LDS staging (rows 8..15 stay zero in x; h/rh garbage stays confined)
  for (int i = tid; i < 16 * PITCH / 2; i += 512) {
    ((int*)h_bf)[i] = 0; ((int*)x_bf)[i] = 0; ((int*)rh_bf)[i] = 0;
  }
  // attention table: att_s[t][r]
  for (int i = tid; i < T_ * NB; i += 512) {
    int r = i / T_, t = i % T_;
    att_s[t][r] = ATT[(size_t)(b0 + r) * T_ + t];
  }
  // x staging geometry: wave w stages row w; lane covers 2 floats
  const int prow = w;
  const int pc2  = (tid & 63) * 2;
  {
    f32x2 xv = *(const f32x2*)(IS + ((size_t)(b0 + prow) * T_ + 0) * U_ + pc2);
    short2_t xb; xb[0] = f2bf(xv[0]); xb[1] = f2bf(xv[1]);
    *(short2_t*)&x_bf[prow][pc2] = xb;
  }
  // register-resident weight B-fragments: Wf[m][kf]
  short8 Wf[6][4];
#pragma unroll
  for (int m = 0; m < 6; ++m)
#pragma unroll
    for (int kf = 0; kf < 4; ++kf)
      Wf[m][kf] = *(const short8*)(WT + ((m * 128 + col) * 128 + kf * 32 + lg * 8));
  // fused biases for this lane's col
  const float bu = bxu[col] + bhu[col];
  const float br = bxr[col] + bhr[col];
  const float bc = bxc[col] + bhc[col];

  const f32x4 fz = {0.0f, 0.0f, 0.0f, 0.0f};
  f32x4 hreg = fz;
  float ureg[4];

  for (int t = 0; t < T_; ++t) {
    __syncthreads();  // h_bf, x_bf ready; rh WAR safe
    // ---- phase 1: A-fragments + projections + u,r gates ----
    short8 xa[4], ha[4];
#pragma unroll
    for (int kf = 0; kf < 4; ++kf) {
      xa[kf] = *(const short8*)&x_bf[l15][kf * 32 + lg * 8];
      ha[kf] = *(const short8*)&h_bf[l15][kf * 32 + lg * 8];
    }
    // prefetch next step's x (h-independent)
    const int tn = (t < T_ - 1) ? t + 1 : t;
    f32x2 xnext = *(const f32x2*)(IS + ((size_t)(b0 + prow) * T_ + tn) * U_ + pc2);

    f32x4 axu = fz, axr = fz, axc = fz, ahu = fz, ahr = fz;
#pragma unroll
    for (int kf = 0; kf < 4; ++kf) {
      axu = __builtin_amdgcn_mfma_f32_16x16x32_bf16(xa[kf], Wf[0][kf], axu, 0, 0, 0);
      axr = __builtin_amdgcn_mfma_f32_16x16x32_bf16(xa[kf], Wf[1][kf], axr, 0, 0, 0);
      axc = __builtin_amdgcn_mfma_f32_16x16x32_bf16(xa[kf], Wf[2][kf], axc, 0, 0, 0);
      ahu = __builtin_amdgcn_mfma_f32_16x16x32_bf16(ha[kf], Wf[3][kf], ahu, 0, 0, 0);
      ahr = __builtin_amdgcn_mfma_f32_16x16x32_bf16(ha[kf], Wf[4][kf], ahr, 0, 0, 0);
    }
#pragma unroll
    for (int rg = 0; rg < 4; ++rg) {
      float ug = sigm(axu[rg] + ahu[rg] + bu);
      float rr = sigm(axr[rg] + ahr[rg] + br);
      ureg[rg] = ug;
      rh_bf[lg * 4 + rg][col] = f2bf(rr * hreg[rg]);
    }
    __syncthreads();  // rh_bf ready; h_bf/x_bf reads done (WAR safe)
    // ---- phase 2: candidate + state update ----
    short8 ra[4];
#pragma unroll
    for (int kf = 0; kf < 4; ++kf) ra[kf] = *(const short8*)&rh_bf[l15][kf * 32 + lg * 8];
    f32x4 ahc = fz;
#pragma unroll
    for (int kf = 0; kf < 4; ++kf)
      ahc = __builtin_amdgcn_mfma_f32_16x16x32_bf16(ra[kf], Wf[5][kf], ahc, 0, 0, 0);
    // attention for this lane's rows: (4*lg+rg)&7 == 4*(lg&1)+rg
    f32x4 a4 = *(const f32x4*)&att_s[t][(lg & 1) * 4];
#pragma unroll
    for (int rg = 0; rg < 4; ++rg) {
      float cc = tanh_fast(axc[rg] + ahc[rg] + bc);
      float au = a4[rg] * ureg[rg];
      float hv = (1.0f - au) * hreg[rg] + au * cc;
      hreg[rg] = hv;
      h_bf[lg * 4 + rg][col] = f2bf(hv);
    }
    // stage x_{t+1}
    {
      short2_t xb; xb[0] = f2bf(xnext[0]); xb[1] = f2bf(xnext[1]);
      *(short2_t*)&x_bf[prow][pc2] = xb;
    }
  }
  // write h_final (fp32, rows 0..7 real)
#pragma unroll
  for (int rg = 0; rg < 4; ++rg) {
    const int row = lg * 4 + rg;
    if (row < NB) out[(size_t)(b0 + row) * U_ + col] = hreg[rg];
  }
}

extern "C" void kernel_launch(void* const* d_in, const int* in_sizes, int n_in,
                              void* d_out, int out_size, void* d_ws, size_t ws_size,
                              hipStream_t stream) {
  const float* IS  = (const float*)d_in[0];
  const float* ATT = (const float*)d_in[1];
  const float* Wxu = (const float*)d_in[2];  const float* bxu = (const float*)d_in[3];
  const float* Whu = (const float*)d_in[4];  const float* bhu = (const float*)d_in[5];
  const float* Wxr = (const float*)d_in[6];  const float* bxr = (const float*)d_in[7];
  const float* Whr = (const float*)d_in[8];  const float* bhr = (const float*)d_in[9];
  const float* Wxc = (const float*)d_in[10]; const float* bxc = (const float*)d_in[11];
  const float* Whc = (const float*)d_in[12]; const float* bhc = (const float*)d_in[13];
  short* WT  = (short*)d_ws;
  float* OUT = (float*)d_out;

  prep_weights<<<dim3(6 * 128), dim3(128), 0, stream>>>(Wxu, Wxr, Wxc, Whu, Whr, Whc, WT);
  augru_scan<<<dim3(B_ / NB), dim3(512), 0, stream>>>(IS, ATT, bxu, bhu, bxr, bhr, bxc, bhc, WT, OUT);
}

// Round 4
// 449.198 us; speedup vs baseline: 1.1733x; 1.0037x over previous
//
#include <hip/hip_runtime.h>
#include <hip/hip_bf16.h>

#define B_  2048
#define T_  200
#define U_  128
#define NB  8      // batch rows per block
#define PITCH 136  // x_bf LDS pitch (bf16 elems)

typedef __attribute__((ext_vector_type(8))) short short8;
typedef __attribute__((ext_vector_type(4))) float f32x4;
typedef __attribute__((ext_vector_type(2))) float f32x2;
typedef __attribute__((ext_vector_type(2))) unsigned uint2v;

static __device__ inline float sigm_pre(float sum, float bS) {
  // sigmoid(sum + b) with bS = b * -log2(e):  1/(1+exp2(fma(sum,-log2e,bS)))
  float e = __builtin_amdgcn_exp2f(fmaf(sum, -1.44269504088896340736f, bS));
  return __builtin_amdgcn_rcpf(1.0f + e);
}
static __device__ inline float tanh_pre(float sum, float bS) {
  // tanh(sum + b) with bS = b * 2log2(e):  1 - 2/(1+exp2(fma(sum,2log2e,bS)))
  float e = __builtin_amdgcn_exp2f(fmaf(sum, 2.88539008177792681472f, bS));
  float r = __builtin_amdgcn_rcpf(1.0f + e);
  return fmaf(-2.0f, r, 1.0f);
}
static __device__ inline unsigned pk2(float a, float b) {
  union { __hip_bfloat162 h; unsigned u; } c;
  float2 t; t.x = a; t.y = b;
  c.h = __float22bfloat162_rn(t);   // v_cvt_pk_bf16_f32, RNE
  return c.u;
}
static __device__ inline short f2bf(float f) {
  union { float f; unsigned u; } v; v.f = f;
  unsigned r = v.u + 0x7FFFu + ((v.u >> 16) & 1u);
  return (short)(r >> 16);
}

// ds_read_b64_tr_b16: per 16-lane group, reads the 128B [4][16]-bf16 tile the
// group's addresses cover; lane receives column (l&15). Per-lane addr =
// tile_base + (l&15)*8; offset: walks sub-tiles.
#define TRFRAG(dst, addr, O0, O1)                                              \
  {                                                                            \
    uint2v _ta, _tb;                                                           \
    asm volatile("ds_read_b64_tr_b16 %0, %1 offset:" O0 : "=v"(_ta) : "v"(addr)); \
    asm volatile("ds_read_b64_tr_b16 %0, %1 offset:" O1 : "=v"(_tb) : "v"(addr)); \
    union { struct { uint2v a, b; } p; short8 s; } _u;                         \
    _u.p.a = _ta; _u.p.b = _tb;                                                \
    dst = _u.s;                                                                \
  }
#define LGKM_WAIT()                                                            \
  asm volatile("s_waitcnt lgkmcnt(0)" ::: "memory");                           \
  __builtin_amdgcn_sched_barrier(0)

// out[m][n][k] = bf16(W_m[k][n]); coalesced reads, strided writes (tiny kernel).
__global__ void prep_weights(const float* __restrict__ Wxu, const float* __restrict__ Wxr,
                             const float* __restrict__ Wxc, const float* __restrict__ Whu,
                             const float* __restrict__ Whr, const float* __restrict__ Whc,
                             short* __restrict__ out) {
  const int m = blockIdx.x >> 7;
  const int k = blockIdx.x & 127;
  const int n = threadIdx.x;
  const float* Wp;
  switch (m) {
    case 0: Wp = Wxu; break; case 1: Wp = Wxr; break; case 2: Wp = Wxc; break;
    case 3: Wp = Whu; break; case 4: Wp = Whr; break; default: Wp = Whc; break;
  }
  out[(m * 128 + n) * 128 + k] = f2bf(Wp[k * 128 + n]);
}

// 8 waves x 16 cols, NB=8 rows/block, 256 blocks (1/CU), 2 waves/SIMD.
// h/rh live in TRANSPOSED bf16 LDS [hidden][row]: the MFMA D-layout (lane owns
// 4 consecutive rows of one col) writes one contiguous b64 (2x v_cvt_pk);
// A-fragments re-materialize via ds_read_b64_tr_b16 (HW transpose read).
// MFMA 16x16x32 bf16: A: lane l = A[l&15][(l>>4)*8+j]; D: lane l reg r = D[4*(l>>4)+r][l&15].
// M-rows 8..15 are benign bounded garbage (x rows 8..15 pinned to zero; convex update).
__global__ __launch_bounds__(512, 2) void augru_scan(
    const float* __restrict__ IS, const float* __restrict__ ATT,
    const float* __restrict__ bxu, const float* __restrict__ bhu,
    const float* __restrict__ bxr, const float* __restrict__ bhr,
    const float* __restrict__ bxc, const float* __restrict__ bhc,
    const short* __restrict__ WT, float* __restrict__ out) {
  __shared__ __align__(128) short h_T[128][16];   // h_T[hidden][row]
  __shared__ __align__(128) short rh_T[128][16];  // (r*h)_T[hidden][row]
  __shared__ __align__(16)  short x_bf[16][PITCH];
  __shared__ __align__(16)  float att_s[T_][NB];

  const int tid  = threadIdx.x;
  const int w    = tid >> 6;
  const int l    = tid & 63;
  const int l15  = l & 15;
  const int lg   = l >> 4;
  const int b0   = blockIdx.x * NB;
  const int col  = w * 16 + l15;

  // zero LDS (x rows 8..15 stay zero; h starts at 0)
  for (int i = tid; i < (128 * 16 * 2 + 16 * PITCH) / 2; i += 512) {
    if (i < 128 * 16 / 2)               ((int*)h_T)[i] = 0;
    else if (i < 128 * 16)              ((int*)rh_T)[i - 128 * 16 / 2] = 0;
    else                                ((int*)x_bf)[i - 128 * 16] = 0;
  }
  for (int i = tid; i < T_ * NB; i += 512) {
    int r = i / T_, t = i % T_;
    att_s[t][r] = ATT[(size_t)(b0 + r) * T_ + t];
  }
  // x staging: wave w stages row w, lane covers 2 consecutive k
  const int prow = w;
  const int pc2  = (tid & 63) * 2;
  const float* xptr = IS + (size_t)(b0 + prow) * T_ * U_ + pc2;
  {
    f32x2 xv = *(const f32x2*)xptr;
    *(unsigned*)&x_bf[prow][pc2] = pk2(xv[0], xv[1]);
  }
  // register-resident weight B-fragments Wf[m][kf]; keep-alive forbids remat
  short8 Wf[6][4];
#pragma unroll
  for (int m = 0; m < 6; ++m)
#pragma unroll
    for (int kf = 0; kf < 4; ++kf)
      Wf[m][kf] = *(const short8*)(WT + ((m * 128 + col) * 128 + kf * 32 + lg * 8));
#pragma unroll
  for (int m = 0; m < 6; ++m)
#pragma unroll
    for (int kf = 0; kf < 4; ++kf) asm volatile("" : "+v"(Wf[m][kf]));

  // pre-scaled fused biases
  const float buS = (bxu[col] + bhu[col]) * -1.44269504088896340736f;
  const float brS = (bxr[col] + bhr[col]) * -1.44269504088896340736f;
  const float bcS = (bxc[col] + bhc[col]) * 2.88539008177792681472f;

  // loop-invariant tr-read addresses (LDS offsets; low 32 bits of flat addr)
  const unsigned trv   = (unsigned)(lg * 256 + l15 * 8);
  const unsigned adr_h = (unsigned)(size_t)(&h_T[0][0]) + trv;
  const unsigned adr_r = (unsigned)(size_t)(&rh_T[0][0]) + trv;

  const f32x4 fz = {0.0f, 0.0f, 0.0f, 0.0f};
  f32x4 hreg = fz;
  float ureg[4];

  for (int t = 0; t < T_; ++t) {
    __syncthreads();
    __builtin_amdgcn_sched_barrier(0);
    // ---- phase 1: load A-frags, 20 MFMA, u/r gates, write rh_T ----
    short8 ha[4], xa[4];
    TRFRAG(ha[0], adr_h, "0",    "128");
    TRFRAG(ha[1], adr_h, "1024", "1152");
    TRFRAG(ha[2], adr_h, "2048", "2176");
    TRFRAG(ha[3], adr_h, "3072", "3200");
#pragma unroll
    for (int kf = 0; kf < 4; ++kf)
      xa[kf] = *(const short8*)&x_bf[l15][kf * 32 + lg * 8];
    // prefetch next x (h-independent)
    const f32x2 xnext = *(const f32x2*)(xptr + (t < T_ - 1 ? (size_t)(t + 1) * U_ : (size_t)t * U_));
    LGKM_WAIT();

    f32x4 axu = fz, axr = fz, axc = fz, ahu = fz, ahr = fz;
#pragma unroll
    for (int kf = 0; kf < 4; ++kf) {
      axu = __builtin_amdgcn_mfma_f32_16x16x32_bf16(xa[kf], Wf[0][kf], axu, 0, 0, 0);
      axr = __builtin_amdgcn_mfma_f32_16x16x32_bf16(xa[kf], Wf[1][kf], axr, 0, 0, 0);
      axc = __builtin_amdgcn_mfma_f32_16x16x32_bf16(xa[kf], Wf[2][kf], axc, 0, 0, 0);
      ahu = __builtin_amdgcn_mfma_f32_16x16x32_bf16(ha[kf], Wf[3][kf], ahu, 0, 0, 0);
      ahr = __builtin_amdgcn_mfma_f32_16x16x32_bf16(ha[kf], Wf[4][kf], ahr, 0, 0, 0);
    }
    float rh[4];
#pragma unroll
    for (int rg = 0; rg < 4; ++rg) {
      ureg[rg] = sigm_pre(axu[rg] + ahu[rg], buS);
      float rr = sigm_pre(axr[rg] + ahr[rg], brS);
      rh[rg]   = rr * hreg[rg];
    }
    {
      uint2v wv; wv[0] = pk2(rh[0], rh[1]); wv[1] = pk2(rh[2], rh[3]);
      *(uint2v*)&rh_T[col][lg * 4] = wv;   // contiguous b64
    }
    __syncthreads();
    __builtin_amdgcn_sched_barrier(0);
    // ---- phase 2: candidate matvec (2 split chains) + state update ----
    short8 ra[4];
    TRFRAG(ra[0], adr_r, "0",    "128");
    TRFRAG(ra[1], adr_r, "1024", "1152");
    TRFRAG(ra[2], adr_r, "2048", "2176");
    TRFRAG(ra[3], adr_r, "3072", "3200");
    const f32x4 a4 = *(const f32x4*)&att_s[t][(lg & 1) * 4];
    LGKM_WAIT();

    f32x4 ahc0 = fz, ahc1 = fz;
    ahc0 = __builtin_amdgcn_mfma_f32_16x16x32_bf16(ra[0], Wf[5][0], ahc0, 0, 0, 0);
    ahc1 = __builtin_amdgcn_mfma_f32_16x16x32_bf16(ra[2], Wf[5][2], ahc1, 0, 0, 0);
    ahc0 = __builtin_amdgcn_mfma_f32_16x16x32_bf16(ra[1], Wf[5][1], ahc0, 0, 0, 0);
    ahc1 = __builtin_amdgcn_mfma_f32_16x16x32_bf16(ra[3], Wf[5][3], ahc1, 0, 0, 0);

    float hv[4];
#pragma unroll
    for (int rg = 0; rg < 4; ++rg) {
      float cc = tanh_pre((axc[rg] + ahc0[rg]) + ahc1[rg], bcS);
      float au = a4[rg] * ureg[rg];
      hv[rg] = fmaf(au, cc - hreg[rg], hreg[rg]);
      hreg[rg] = hv[rg];
    }
    {
      uint2v wv; wv[0] = pk2(hv[0], hv[1]); wv[1] = pk2(hv[2], hv[3]);
      *(uint2v*)&h_T[col][lg * 4] = wv;
    }
    // stage x_{t+1}
    *(unsigned*)&x_bf[prow][pc2] = pk2(xnext[0], xnext[1]);
  }
  // write h_final (fp32, rows 0..7 real)
#pragma unroll
  for (int rg = 0; rg < 4; ++rg) {
    const int row = lg * 4 + rg;
    if (row < NB) out[(size_t)(b0 + row) * U_ + col] = hreg[rg];
  }
}

extern "C" void kernel_launch(void* const* d_in, const int* in_sizes, int n_in,
                              void* d_out, int out_size, void* d_ws, size_t ws_size,
                              hipStream_t stream) {
  const float* IS  = (const float*)d_in[0];
  const float* ATT = (const float*)d_in[1];
  const float* Wxu = (const float*)d_in[2];  const float* bxu = (const float*)d_in[3];
  const float* Whu = (const float*)d_in[4];  const float* bhu = (const float*)d_in[5];
  const float* Wxr = (const float*)d_in[6];  const float* bxr = (const float*)d_in[7];
  const float* Whr = (const float*)d_in[8];  const float* bhr = (const float*)d_in[9];
  const float* Wxc = (const float*)d_in[10]; const float* bxc = (const float*)d_in[11];
  const float* Whc = (const float*)d_in[12]; const float* bhc = (const float*)d_in[13];
  short* WT  = (short*)d_ws;
  float* OUT = (float*)d_out;

  prep_weights<<<dim3(6 * 128), dim3(128), 0, stream>>>(Wxu, Wxr, Wxc, Whu, Whr, Whc, WT);
  augru_scan<<<dim3(B_ / NB), dim3(512), 0, stream>>>(IS, ATT, bxu, bhu, bxr, bhr, bxc, bhc, WT, OUT);
}